// Round 4
// baseline (4743.979 us; speedup 1.0000x reference)
//
#include <hip/hip_runtime.h>

#define NQ 512
#define NC 128
#define EC 32
#define OC 64

__device__ __forceinline__ float silu_f(float x) {
    return x / (1.0f + __expf(-x));
}

// ---------------------------------------------------------------------------
// Prepass: decode virtual_mask (unknown upload layout: u8 / int32 / f32).
// ---------------------------------------------------------------------------
__global__ void decode_mask_kernel(const unsigned char* __restrict__ raw,
                                   int* __restrict__ out, int n) {
    __shared__ int cntA, cntN;
    int t = threadIdx.x;
    if (t == 0) { cntA = 0; cntN = 0; }
    __syncthreads();
    int la = 0, ln = 0;
    for (int idx = t; idx < n; idx += blockDim.x) {
        unsigned char v = raw[idx];
        if (v) { if ((idx & 3) == 0) la++; else ln++; }
    }
    if (la) atomicAdd(&cntA, la);
    if (ln) atomicAdd(&cntN, ln);
    __syncthreads();
    int a = cntA, nn = cntN;
    for (int i = t; i < n; i += blockDim.x) {
        int v;
        if (a > 0 && nn == 0)      v = ((const int*)raw)[i];             // int32
        else if (a == 0)           v = (((const float*)raw)[i] != 0.0f); // f32
        else                       v = (raw[i] != 0);                    // u8
        out[i] = v;
    }
}

// ---------------------------------------------------------------------------
// Node path: one block per (b,i), 128 threads. Also precomputes
// q1 = n1@W_f1, q2 = n2@W_f1 + b_f1 (per node) so the edge kernel never
// runs the t1 GEMV.
// ---------------------------------------------------------------------------
__global__ __launch_bounds__(128) void node_kernel(
    const float* __restrict__ node, const float* __restrict__ edge,
    const int* __restrict__ block_id, const int* __restrict__ vmd,
    const float* __restrict__ W_nt, const float* __restrict__ b_nt,
    const float* __restrict__ W_n1, const float* __restrict__ b_n1,
    const float* __restrict__ W_f1, const float* __restrict__ b_f1,
    const float* __restrict__ W_no1, const float* __restrict__ b_no1,
    const float* __restrict__ g_no, const float* __restrict__ be_no,
    const float* __restrict__ W_no2, const float* __restrict__ b_no2,
    float* __restrict__ n_ws, float* __restrict__ q1_ws, float* __restrict__ q2_ws,
    float* __restrict__ out_node) {
    const int bi = blockIdx.x;
    const int b = bi >> 9, i = bi & (NQ - 1);
    const int t = threadIdx.x;

    __shared__ int   sid[NQ];
    __shared__ int   svm[NQ];
    __shared__ float xcat[192];
    __shared__ float rin[4][32];
    __shared__ float rout[4][32];
    __shared__ int   rcin[4], rcout[4];
    __shared__ float hbuf[128];
    __shared__ float red[128];
    __shared__ float nbuf[128];
    __shared__ float zbuf[128];

    for (int k = t; k < NQ; k += 128) {
        sid[k] = block_id[b * NQ + k];
        svm[k] = vmd[b * NQ + k];
    }
    __syncthreads();

    const int  id_i = sid[i];
    const int  vm_i = svm[i];
    const bool nm_i = (id_i >= 0);

    const int c = t & 31, g = t >> 5;
    float accin = 0.f, accout = 0.f;
    int   cntin = 0, cntout = 0;
    const float* erow = edge + ((size_t)(b * NQ + i)) * NQ * EC; // edge[b,i,j,c]
    const float* ecol = edge + ((size_t)b * NQ * NQ + i) * EC;   // edge[b,j,i,c]
    for (int j = g; j < NQ; j += 4) {
        int  id_j = sid[j];
        bool nm_j = (id_j >= 0);
        bool pv = nm_i && nm_j;
        bool cin  = pv && ((id_i > id_j) || (id_i == id_j && !vm_i));
        bool cout = pv && ((id_j > id_i) || (id_j == id_i && !svm[j]));
        if (cin)  { accin  += erow[j * EC + c]; cntin++; }
        if (cout) { accout += ecol[(size_t)j * NQ * EC + c]; cntout++; }
    }
    rin[g][c] = accin;
    rout[g][c] = accout;
    if (c == 0) { rcin[g] = cntin; rcout[g] = cntout; }
    __syncthreads();

    if (t < 32) {
        float s = rin[0][t] + rin[1][t] + rin[2][t] + rin[3][t];
        float cnt = (float)(rcin[0] + rcin[1] + rcin[2] + rcin[3]);
        xcat[t] = s / fmaxf(cnt, 1.0f);
    } else if (t < 64) {
        int tc = t - 32;
        float s = rout[0][tc] + rout[1][tc] + rout[2][tc] + rout[3][tc];
        float cnt = (float)(rcout[0] + rcout[1] + rcout[2] + rcout[3]);
        xcat[t] = s / fmaxf(cnt, 1.0f);
    }
    {
        float nv = node[(size_t)(b * NQ + i) * NC + t];
        xcat[64 + t] = nm_i ? nv : 0.0f;
    }
    __syncthreads();

    // h = silu(xcat @ W_nt + b_nt) * nm
    float acc = b_nt[t];
    #pragma unroll 4
    for (int k = 0; k < 192; ++k) acc += xcat[k] * W_nt[k * NC + t];
    float h = nm_i ? silu_f(acc) : 0.0f;
    hbuf[t] = h;
    __syncthreads();

    // n = h @ W_n1 + b_n1 ; u = h @ W_no1 + b_no1
    float accn = b_n1[t];
    float u = b_no1[t];
    #pragma unroll 4
    for (int k = 0; k < 128; ++k) {
        float hk = hbuf[k];
        accn += hk * W_n1[k * 128 + t];
        u    += hk * W_no1[k * 128 + t];
    }
    n_ws[(size_t)(b * NQ + i) * 128 + t] = accn;

    nbuf[t] = accn;
    red[t] = u;
    __syncthreads();

    // q1[c] = sum_k n1[k] W_f1[k,c]; q2[c] = b_f1[c] + sum_k n2[k] W_f1[k,c]
    {
        int cc = t & 63;
        const float* src = nbuf + ((t < 64) ? 0 : 64);
        float q = (t < 64) ? 0.0f : b_f1[cc];
        #pragma unroll 4
        for (int k = 0; k < 64; ++k) q += src[k] * W_f1[k * 64 + cc];
        float* dst = (t < 64) ? q1_ws : q2_ws;
        dst[(size_t)(b * NQ + i) * 64 + cc] = q;
    }

    // LayerNorm over 128 channels (across threads)
    for (int s = 64; s > 0; s >>= 1) { if (t < s) red[t] += red[t + s]; __syncthreads(); }
    float m = red[0] * (1.0f / 128.0f);
    __syncthreads();
    float d = u - m;
    red[t] = d * d;
    __syncthreads();
    for (int s = 64; s > 0; s >>= 1) { if (t < s) red[t] += red[t + s]; __syncthreads(); }
    float var = red[0] * (1.0f / 128.0f);
    float z = silu_f(d * rsqrtf(var + 1e-5f) * g_no[t] + be_no[t]);
    zbuf[t] = z;
    __syncthreads();

    if (t < 10) {
        float o = b_no2[t];
        #pragma unroll 4
        for (int k2 = 0; k2 < 128; ++k2) o += zbuf[k2] * W_no2[k2 * 10 + t];
        out_node[(size_t)(b * NQ + i) * 10 + t] = nm_i ? o : 0.0f;
    }
}

// ---------------------------------------------------------------------------
// Edge path. lane = unordered pair {i,j}. All register arrays statically
// indexed (no scratch). e0 parked in a private stride-65 LDS row
// (bank shift 1 -> conflict-free b32 access). Weights consumed via
// wave-uniform s_load. es[64] accumulates both directions in registers.
// ---------------------------------------------------------------------------
__global__ __launch_bounds__(128, 2) void edge_kernel(
    const float* __restrict__ edge, const int* __restrict__ block_id,
    const int* __restrict__ vmd, const float* __restrict__ n_ws,
    const float* __restrict__ q1_ws, const float* __restrict__ q2_ws,
    const float* __restrict__ W_e1, const float* __restrict__ b_e1,
    const float* __restrict__ W_f2, const float* __restrict__ b_f2,
    const float* __restrict__ W_eo1, const float* __restrict__ b_eo1,
    const float* __restrict__ g_eo, const float* __restrict__ be_eo,
    const float* __restrict__ W_eo2, const float* __restrict__ b_eo2,
    float* __restrict__ out_edge) {
    __shared__ float sbuf[128 * 65];
    float* lrow = sbuf + threadIdx.x * 65;

    const int P = blockIdx.x * 128 + threadIdx.x;
    const int b = P / (NQ * 257);
    int r = P - b * (NQ * 257);
    const int i = r / 257;
    const int dj = r - i * 257;
    const int j = (i + dj) & (NQ - 1);
    const bool valid = (dj != 256) || (i < 256);

    const int  id_i = block_id[b * NQ + i], id_j = block_id[b * NQ + j];
    const int  vm_i = vmd[b * NQ + i],      vm_j = vmd[b * NQ + j];
    const bool nm_i = (id_i >= 0), nm_j = (id_j >= 0);
    const bool em = nm_i && nm_j && ((id_i != id_j) || (!vm_i) || (!vm_j));

    const float* eij = edge + (((size_t)(b * NQ) + i) * NQ + j) * EC;
    const float* eji = edge + (((size_t)(b * NQ) + j) * NQ + i) * EC;
    const float* nb0 = n_ws  + (size_t)b * NQ * 128;
    const float* q1t = q1_ws + (size_t)b * NQ * 64;
    const float* q2t = q2_ws + (size_t)b * NQ * 64;

    float es[OC];
    #pragma unroll
    for (int cc = 0; cc < OC; ++cc) es[cc] = 0.0f;

    #pragma unroll 1
    for (int d = 0; d < 2; ++d) {
        const float* ein_p = d ? eji : eij;
        const int ia = d ? i : j;   // index feeding q1 / n1
        const int ib = d ? j : i;   // index feeding q2 / n2
        const float* pq1 = q1t + (size_t)ia * 64;
        const float* pq2 = q2t + (size_t)ib * 64;
        const float* pn1 = nb0 + (size_t)ia * 128;
        const float* pn2 = nb0 + (size_t)ib * 128 + 64;

        // --- phase 1: e0 = e_in @ W_e1 + b_e1  ->  LDS row ---
        float ein[EC];
        #pragma unroll
        for (int q4 = 0; q4 < 8; ++q4) {
            float4 v = ((const float4*)ein_p)[q4];
            ein[q4 * 4 + 0] = v.x; ein[q4 * 4 + 1] = v.y;
            ein[q4 * 4 + 2] = v.z; ein[q4 * 4 + 3] = v.w;
        }
        #pragma unroll
        for (int cb = 0; cb < 4; ++cb) {
            float acc[16];
            #pragma unroll
            for (int cc = 0; cc < 16; ++cc) acc[cc] = b_e1[cb * 16 + cc];
            #pragma unroll
            for (int k = 0; k < EC; ++k) {
                const float* wr = W_e1 + k * OC + cb * 16;
                #pragma unroll
                for (int cc = 0; cc < 16; ++cc) acc[cc] += ein[k] * wr[cc];
            }
            #pragma unroll
            for (int cc = 0; cc < 16; ++cc) lrow[cb * 16 + cc] = acc[cc];
        }

        // --- phase 2: t2 = silu(e0 @ W_f2 + b_f2); combine ---
        #pragma unroll
        for (int cb = 0; cb < 4; ++cb) {
            float acc2[16];
            #pragma unroll
            for (int cc = 0; cc < 16; ++cc) acc2[cc] = b_f2[cb * 16 + cc];
            #pragma unroll 2
            for (int kb = 0; kb < 16; ++kb) {
                float e0k[4];
                #pragma unroll
                for (int u = 0; u < 4; ++u) e0k[u] = lrow[kb * 4 + u];
                #pragma unroll
                for (int u = 0; u < 4; ++u) {
                    const float* wr = W_f2 + (kb * 4 + u) * OC + cb * 16;
                    #pragma unroll
                    for (int cc = 0; cc < 16; ++cc) acc2[cc] += e0k[u] * wr[cc];
                }
            }
            float q1c[16], q2c[16], n1c[16], n2c[16];
            #pragma unroll
            for (int q4 = 0; q4 < 4; ++q4) {
                float4 v1 = ((const float4*)(pq1 + cb * 16))[q4];
                float4 v2 = ((const float4*)(pq2 + cb * 16))[q4];
                float4 v3 = ((const float4*)(pn1 + cb * 16))[q4];
                float4 v4 = ((const float4*)(pn2 + cb * 16))[q4];
                q1c[q4*4+0]=v1.x; q1c[q4*4+1]=v1.y; q1c[q4*4+2]=v1.z; q1c[q4*4+3]=v1.w;
                q2c[q4*4+0]=v2.x; q2c[q4*4+1]=v2.y; q2c[q4*4+2]=v2.z; q2c[q4*4+3]=v2.w;
                n1c[q4*4+0]=v3.x; n1c[q4*4+1]=v3.y; n1c[q4*4+2]=v3.z; n1c[q4*4+3]=v3.w;
                n2c[q4*4+0]=v4.x; n2c[q4*4+1]=v4.y; n2c[q4*4+2]=v4.z; n2c[q4*4+3]=v4.w;
            }
            #pragma unroll
            for (int cc = 0; cc < 16; ++cc) {
                float t1 = silu_f(q1c[cc] + q2c[cc]);
                float t2 = silu_f(acc2[cc]);
                float np = n1c[cc] + n2c[cc];
                float e0 = lrow[cb * 16 + cc];
                es[cb * 16 + cc] += silu_f(np + e0 + t1 * t2);
            }
        }
    }

    // --- eo1 GEMV: y = es @ W_eo1 + b_eo1 (fully unrolled, es in regs) ---
    float y[32];
    #pragma unroll
    for (int cc = 0; cc < 32; ++cc) y[cc] = b_eo1[cc];
    #pragma unroll
    for (int k = 0; k < OC; ++k) {
        const float* wr = W_eo1 + k * 32;
        #pragma unroll
        for (int cc = 0; cc < 32; ++cc) y[cc] += es[k] * wr[cc];
    }

    // LayerNorm (lane-local over 32) + silu + eo2
    float mean = 0.f;
    #pragma unroll
    for (int cc = 0; cc < 32; ++cc) mean += y[cc];
    mean *= (1.0f / 32.0f);
    float var = 0.f;
    #pragma unroll
    for (int cc = 0; cc < 32; ++cc) { float dd = y[cc] - mean; var += dd * dd; }
    var *= (1.0f / 32.0f);
    float rs = rsqrtf(var + 1e-5f);

    float o[5];
    #pragma unroll
    for (int q = 0; q < 5; ++q) o[q] = b_eo2[q];
    #pragma unroll
    for (int cc = 0; cc < 32; ++cc) {
        float z = silu_f((y[cc] - mean) * rs * g_eo[cc] + be_eo[cc]);
        #pragma unroll
        for (int q = 0; q < 5; ++q) o[q] += z * W_eo2[cc * 5 + q];
    }

    if (valid) {
        float* oe1 = out_edge + (((size_t)(b * NQ) + i) * NQ + j) * 5;
        float* oe2 = out_edge + (((size_t)(b * NQ) + j) * NQ + i) * 5;
        #pragma unroll
        for (int q = 0; q < 5; ++q) {
            float v = em ? o[q] : 0.0f;
            oe1[q] = v;
            oe2[q] = v;
        }
    }
}

extern "C" void kernel_launch(void* const* d_in, const int* in_sizes, int n_in,
                              void* d_out, int out_size, void* d_ws, size_t ws_size,
                              hipStream_t stream) {
    const float* node     = (const float*)d_in[0];
    const float* edge     = (const float*)d_in[1];
    const int*   block_id = (const int*)d_in[2];
    const void*  vm_raw   = d_in[3];
    const float* W_nt  = (const float*)d_in[4];
    const float* b_nt  = (const float*)d_in[5];
    const float* W_n1  = (const float*)d_in[6];
    const float* b_n1  = (const float*)d_in[7];
    const float* W_e1  = (const float*)d_in[8];
    const float* b_e1  = (const float*)d_in[9];
    const float* W_f1  = (const float*)d_in[10];
    const float* b_f1  = (const float*)d_in[11];
    const float* W_f2  = (const float*)d_in[12];
    const float* b_f2  = (const float*)d_in[13];
    const float* W_no1 = (const float*)d_in[14];
    const float* b_no1 = (const float*)d_in[15];
    const float* g_no  = (const float*)d_in[16];
    const float* be_no = (const float*)d_in[17];
    const float* W_no2 = (const float*)d_in[18];
    const float* b_no2 = (const float*)d_in[19];
    const float* W_eo1 = (const float*)d_in[20];
    const float* b_eo1 = (const float*)d_in[21];
    const float* g_eo  = (const float*)d_in[22];
    const float* be_eo = (const float*)d_in[23];
    const float* W_eo2 = (const float*)d_in[24];
    const float* b_eo2 = (const float*)d_in[25];

    char* ws = (char*)d_ws;
    int*   vmd  = (int*)ws;                         // 8 KB
    float* n_ws = (float*)(ws + 8192);              // 1 MB
    float* q1_ws = (float*)(ws + 8192 + (1 << 20)); // 512 KB
    float* q2_ws = (float*)(ws + 8192 + (1 << 20) + (512 << 10));
    float* out_node = (float*)d_out;
    float* out_edge = out_node + 4 * 512 * 10;

    decode_mask_kernel<<<1, 256, 0, stream>>>((const unsigned char*)vm_raw, vmd, 4 * 512);
    node_kernel<<<4 * 512, 128, 0, stream>>>(
        node, edge, block_id, vmd,
        W_nt, b_nt, W_n1, b_n1, W_f1, b_f1, W_no1, b_no1, g_no, be_no, W_no2, b_no2,
        n_ws, q1_ws, q2_ws, out_node);
    edge_kernel<<<(4 * 512 * 257) / 128, 128, 0, stream>>>(
        edge, block_id, vmd, n_ws, q1_ws, q2_ws,
        W_e1, b_e1, W_f2, b_f2,
        W_eo1, b_eo1, g_eo, be_eo, W_eo2, b_eo2, out_edge);
}

// Round 6
// 598.076 us; speedup vs baseline: 7.9321x; 7.9321x over previous
//
#include <hip/hip_runtime.h>

#define NQ 512
#define NC 128
#define EC 32
#define OC 64

__device__ __forceinline__ float silu_f(float x) {
    return x / (1.0f + __expf(-x));
}

// ---------------------------------------------------------------------------
// Prepass: decode virtual_mask (unknown upload layout: u8 / int32 / f32).
// ---------------------------------------------------------------------------
__global__ void decode_mask_kernel(const unsigned char* __restrict__ raw,
                                   int* __restrict__ out, int n) {
    __shared__ int cntA, cntN;
    int t = threadIdx.x;
    if (t == 0) { cntA = 0; cntN = 0; }
    __syncthreads();
    int la = 0, ln = 0;
    for (int idx = t; idx < n; idx += blockDim.x) {
        unsigned char v = raw[idx];
        if (v) { if ((idx & 3) == 0) la++; else ln++; }
    }
    if (la) atomicAdd(&cntA, la);
    if (ln) atomicAdd(&cntN, ln);
    __syncthreads();
    int a = cntA, nn = cntN;
    for (int i = t; i < n; i += blockDim.x) {
        int v;
        if (a > 0 && nn == 0)      v = ((const int*)raw)[i];             // int32
        else if (a == 0)           v = (((const float*)raw)[i] != 0.0f); // f32
        else                       v = (raw[i] != 0);                    // u8
        out[i] = v;
    }
}

// ---------------------------------------------------------------------------
// Node path: one block per (b,i), 128 threads. Also precomputes
// q1 = n1@W_f1, q2 = n2@W_f1 + b_f1 per node (kills the t1 GEMV in edge path).
// ---------------------------------------------------------------------------
__global__ __launch_bounds__(128) void node_kernel(
    const float* __restrict__ node, const float* __restrict__ edge,
    const int* __restrict__ block_id, const int* __restrict__ vmd,
    const float* __restrict__ W_nt, const float* __restrict__ b_nt,
    const float* __restrict__ W_n1, const float* __restrict__ b_n1,
    const float* __restrict__ W_f1, const float* __restrict__ b_f1,
    const float* __restrict__ W_no1, const float* __restrict__ b_no1,
    const float* __restrict__ g_no, const float* __restrict__ be_no,
    const float* __restrict__ W_no2, const float* __restrict__ b_no2,
    float* __restrict__ n_ws, float* __restrict__ q1_ws, float* __restrict__ q2_ws,
    float* __restrict__ out_node) {
    const int bi = blockIdx.x;
    const int b = bi >> 9, i = bi & (NQ - 1);
    const int t = threadIdx.x;

    __shared__ int   sid[NQ];
    __shared__ int   svm[NQ];
    __shared__ float xcat[192];
    __shared__ float rin[4][32];
    __shared__ float rout[4][32];
    __shared__ int   rcin[4], rcout[4];
    __shared__ float hbuf[128];
    __shared__ float red[128];
    __shared__ float nbuf[128];
    __shared__ float zbuf[128];

    for (int k = t; k < NQ; k += 128) {
        sid[k] = block_id[b * NQ + k];
        svm[k] = vmd[b * NQ + k];
    }
    __syncthreads();

    const int  id_i = sid[i];
    const int  vm_i = svm[i];
    const bool nm_i = (id_i >= 0);

    const int c = t & 31, g = t >> 5;
    float accin = 0.f, accout = 0.f;
    int   cntin = 0, cntout = 0;
    const float* erow = edge + ((size_t)(b * NQ + i)) * NQ * EC; // edge[b,i,j,c]
    const float* ecol = edge + ((size_t)b * NQ * NQ + i) * EC;   // edge[b,j,i,c]
    for (int j = g; j < NQ; j += 4) {
        int  id_j = sid[j];
        bool nm_j = (id_j >= 0);
        bool pv = nm_i && nm_j;
        bool cin  = pv && ((id_i > id_j) || (id_i == id_j && !vm_i));
        bool cout = pv && ((id_j > id_i) || (id_j == id_i && !svm[j]));
        if (cin)  { accin  += erow[j * EC + c]; cntin++; }
        if (cout) { accout += ecol[(size_t)j * NQ * EC + c]; cntout++; }
    }
    rin[g][c] = accin;
    rout[g][c] = accout;
    if (c == 0) { rcin[g] = cntin; rcout[g] = cntout; }
    __syncthreads();

    if (t < 32) {
        float s = rin[0][t] + rin[1][t] + rin[2][t] + rin[3][t];
        float cnt = (float)(rcin[0] + rcin[1] + rcin[2] + rcin[3]);
        xcat[t] = s / fmaxf(cnt, 1.0f);
    } else if (t < 64) {
        int tc = t - 32;
        float s = rout[0][tc] + rout[1][tc] + rout[2][tc] + rout[3][tc];
        float cnt = (float)(rcout[0] + rcout[1] + rcout[2] + rcout[3]);
        xcat[t] = s / fmaxf(cnt, 1.0f);
    }
    {
        float nv = node[(size_t)(b * NQ + i) * NC + t];
        xcat[64 + t] = nm_i ? nv : 0.0f;
    }
    __syncthreads();

    // h = silu(xcat @ W_nt + b_nt) * nm
    float acc = b_nt[t];
    #pragma unroll 4
    for (int k = 0; k < 192; ++k) acc += xcat[k] * W_nt[k * NC + t];
    float h = nm_i ? silu_f(acc) : 0.0f;
    hbuf[t] = h;
    __syncthreads();

    // n = h @ W_n1 + b_n1 ; u = h @ W_no1 + b_no1
    float accn = b_n1[t];
    float u = b_no1[t];
    #pragma unroll 4
    for (int k = 0; k < 128; ++k) {
        float hk = hbuf[k];
        accn += hk * W_n1[k * 128 + t];
        u    += hk * W_no1[k * 128 + t];
    }
    n_ws[(size_t)(b * NQ + i) * 128 + t] = accn;

    nbuf[t] = accn;
    red[t] = u;
    __syncthreads();

    // q1[c] = sum_k n1[k] W_f1[k,c]; q2[c] = b_f1[c] + sum_k n2[k] W_f1[k,c]
    {
        int cc = t & 63;
        const float* src = nbuf + ((t < 64) ? 0 : 64);
        float q = (t < 64) ? 0.0f : b_f1[cc];
        #pragma unroll 4
        for (int k = 0; k < 64; ++k) q += src[k] * W_f1[k * 64 + cc];
        float* dst = (t < 64) ? q1_ws : q2_ws;
        dst[(size_t)(b * NQ + i) * 64 + cc] = q;
    }

    // LayerNorm over 128 channels (across threads)
    for (int s = 64; s > 0; s >>= 1) { if (t < s) red[t] += red[t + s]; __syncthreads(); }
    float m = red[0] * (1.0f / 128.0f);
    __syncthreads();
    float d = u - m;
    red[t] = d * d;
    __syncthreads();
    for (int s = 64; s > 0; s >>= 1) { if (t < s) red[t] += red[t + s]; __syncthreads(); }
    float var = red[0] * (1.0f / 128.0f);
    float z = silu_f(d * rsqrtf(var + 1e-5f) * g_no[t] + be_no[t]);
    zbuf[t] = z;
    __syncthreads();

    if (t < 10) {
        float o = b_no2[t];
        #pragma unroll 4
        for (int k2 = 0; k2 < 128; ++k2) o += zbuf[k2] * W_no2[k2 * 10 + t];
        out_node[(size_t)(b * NQ + i) * 10 + t] = nm_i ? o : 0.0f;
    }
}

// ---------------------------------------------------------------------------
// Edge path, wave-specialized: block = 256 threads = 4 waves, 64 pairs.
// Wave w owns channels [16w,16w+16); lane p owns pair p. Weights are
// wave-uniform -> SGPR; pair vectors live in LDS transposed [k][p] so all
// lane accesses are stride-1 (conflict-free). Per-lane live state ~80 VGPR.
// Pair coverage: main blocks: i fixed, dj = 64m+p in [0,256); tail blocks:
// dj = 256 for i in [0,256). Each unordered pair (incl. diag) exactly once.
// ---------------------------------------------------------------------------
__global__ __launch_bounds__(256, 4) void edge_kernel(
    const float* __restrict__ edge, const int* __restrict__ block_id,
    const int* __restrict__ vmd, const float* __restrict__ n_ws,
    const float* __restrict__ q1_ws, const float* __restrict__ q2_ws,
    const float* __restrict__ W_e1, const float* __restrict__ b_e1,
    const float* __restrict__ W_f2, const float* __restrict__ b_f2,
    const float* __restrict__ W_eo1, const float* __restrict__ b_eo1,
    const float* __restrict__ g_eo, const float* __restrict__ be_eo,
    const float* __restrict__ W_eo2, const float* __restrict__ b_eo2,
    float* __restrict__ out_edge) {
    __shared__ float einT[32][64];   // staged edge row, transposed
    __shared__ float e0T[64][64];    // e0 (later es), transposed
    __shared__ float red2[2][4][64]; // LN partial sums
    __shared__ float oBuf[4][64][5]; // eo2 partials

    const int tid = threadIdx.x;
    const int p = tid & 63;
    const int w = __builtin_amdgcn_readfirstlane(tid >> 6);
    const int bid = blockIdx.x;

    // block -> pair-set decode
    int b, ib0, jb0;
    bool tail;
    if (bid < 8192) {
        b = bid >> 11;
        int rem = bid & 2047;
        ib0 = rem >> 2;            // fixed i
        jb0 = ib0 + (rem & 3) * 64;
        tail = false;
    } else {
        int t2 = bid - 8192;
        b = t2 >> 2;
        ib0 = (t2 & 3) * 64;       // i = ib0 + p
        jb0 = 0;
        tail = true;
    }
    const int i_p = tail ? (ib0 + p) : ib0;
    const int j_p = tail ? (i_p + 256) : ((jb0 + p) & (NQ - 1));

    const float* nb0 = n_ws  + (size_t)b * NQ * 128;
    const float* q1t = q1_ws + (size_t)b * NQ * 64;
    const float* q2t = q2_ws + (size_t)b * NQ * 64;

    float es[16];
    #pragma unroll
    for (int u = 0; u < 16; ++u) es[u] = 0.0f;

    #pragma unroll 1
    for (int d = 0; d < 2; ++d) {
        // ---- stage ein (transposed) : 256 threads, pr = tid>>2, u = tid&3 ----
        {
            const int pr = tid >> 2, u = tid & 3;
            const int i_r = tail ? (ib0 + pr) : ib0;
            const int j_r = tail ? (i_r + 256) : ((jb0 + pr) & (NQ - 1));
            const size_t rowbase = d == 0
                ? (((size_t)(b * NQ) + i_r) * NQ + j_r) * EC
                : (((size_t)(b * NQ) + j_r) * NQ + i_r) * EC;
            const float4* src = (const float4*)(edge + rowbase);
            float4 v0 = src[u];
            float4 v1 = src[u + 4];
            einT[4 * u + 0][pr] = v0.x; einT[4 * u + 1][pr] = v0.y;
            einT[4 * u + 2][pr] = v0.z; einT[4 * u + 3][pr] = v0.w;
            einT[4 * (u + 4) + 0][pr] = v1.x; einT[4 * (u + 4) + 1][pr] = v1.y;
            einT[4 * (u + 4) + 2][pr] = v1.z; einT[4 * (u + 4) + 3][pr] = v1.w;
        }
        __syncthreads();

        // ---- phase 1: e0 chunk = ein @ W_e1 + b_e1 (SGPR weights) ----
        float e0c[16];
        #pragma unroll
        for (int u = 0; u < 16; ++u) e0c[u] = b_e1[w * 16 + u];
        #pragma unroll 4
        for (int k = 0; k < EC; ++k) {
            float ek = einT[k][p];
            const float* wr = W_e1 + k * OC + w * 16;
            #pragma unroll
            for (int u = 0; u < 16; ++u) e0c[u] += ek * wr[u];
        }
        #pragma unroll
        for (int u = 0; u < 16; ++u) e0T[w * 16 + u][p] = e0c[u];
        __syncthreads();

        // ---- phase 2: t2 chunk = e0 @ W_f2 + b_f2 (full-k from LDS) ----
        float t2a[16];
        #pragma unroll
        for (int u = 0; u < 16; ++u) t2a[u] = b_f2[w * 16 + u];
        #pragma unroll 4
        for (int k = 0; k < OC; ++k) {
            float e0k = e0T[k][p];
            const float* wr = W_f2 + k * OC + w * 16;
            #pragma unroll
            for (int u = 0; u < 16; ++u) t2a[u] += e0k * wr[u];
        }

        // ---- combine: es += silu(np + e0 + silu(q1+q2)*silu(t2)) ----
        {
            const int ja = d == 0 ? j_p : i_p;   // feeds n1/q1
            const int ib = d == 0 ? i_p : j_p;   // feeds n2/q2
            const float* pq1 = q1t + (size_t)ja * 64 + w * 16;
            const float* pq2 = q2t + (size_t)ib * 64 + w * 16;
            const float* pn1 = nb0 + (size_t)ja * 128 + w * 16;
            const float* pn2 = nb0 + (size_t)ib * 128 + 64 + w * 16;
            #pragma unroll
            for (int v4 = 0; v4 < 4; ++v4) {
                float4 a1 = ((const float4*)pq1)[v4];
                float4 a2 = ((const float4*)pq2)[v4];
                float4 b1 = ((const float4*)pn1)[v4];
                float4 b2 = ((const float4*)pn2)[v4];
                float q1r[4] = {a1.x, a1.y, a1.z, a1.w};
                float q2r[4] = {a2.x, a2.y, a2.z, a2.w};
                float n1r[4] = {b1.x, b1.y, b1.z, b1.w};
                float n2r[4] = {b2.x, b2.y, b2.z, b2.w};
                #pragma unroll
                for (int r = 0; r < 4; ++r) {
                    int c = v4 * 4 + r;
                    float t1 = silu_f(q1r[r] + q2r[r]);
                    float t2 = silu_f(t2a[c]);
                    es[c] += silu_f(n1r[r] + n2r[r] + e0c[c] + t1 * t2);
                }
            }
        }
        __syncthreads();   // einT/e0T safe to overwrite next iteration
    }

    // ---- write es (transposed) for the eo1 full-k GEMV ----
    #pragma unroll
    for (int u = 0; u < 16; ++u) e0T[w * 16 + u][p] = es[u];
    __syncthreads();

    // ---- eo1: y chunk (8 channels per wave) = es @ W_eo1 + b_eo1 ----
    const int c0 = w * 8;
    float y[8];
    #pragma unroll
    for (int u = 0; u < 8; ++u) y[u] = b_eo1[c0 + u];
    #pragma unroll 4
    for (int k = 0; k < OC; ++k) {
        float esk = e0T[k][p];
        const float* wr = W_eo1 + k * 32 + c0;
        #pragma unroll
        for (int u = 0; u < 8; ++u) y[u] += esk * wr[u];
    }

    // ---- LayerNorm partials across waves ----
    float s1 = 0.f, s2 = 0.f;
    #pragma unroll
    for (int u = 0; u < 8; ++u) { s1 += y[u]; s2 += y[u] * y[u]; }
    red2[0][w][p] = s1;
    red2[1][w][p] = s2;
    __syncthreads();
    float S1 = red2[0][0][p] + red2[0][1][p] + red2[0][2][p] + red2[0][3][p];
    float S2 = red2[1][0][p] + red2[1][1][p] + red2[1][2][p] + red2[1][3][p];
    float mean = S1 * (1.0f / 32.0f);
    float var  = S2 * (1.0f / 32.0f) - mean * mean;
    float rs = rsqrtf(var + 1e-5f);

    // ---- z + eo2 partial ----
    float o[5] = {0.f, 0.f, 0.f, 0.f, 0.f};
    #pragma unroll
    for (int u = 0; u < 8; ++u) {
        float z = silu_f((y[u] - mean) * rs * g_eo[c0 + u] + be_eo[c0 + u]);
        const float* wr = W_eo2 + (c0 + u) * 5;
        #pragma unroll
        for (int q = 0; q < 5; ++q) o[q] += z * wr[q];
    }
    #pragma unroll
    for (int q = 0; q < 5; ++q) oBuf[w][p][q] = o[q];
    __syncthreads();

    // ---- wave 0: sum partials, mask, write both (i,j) and (j,i) ----
    if (w == 0) {
        const int id_i = block_id[b * NQ + i_p], id_j = block_id[b * NQ + j_p];
        const int vm_i = vmd[b * NQ + i_p],      vm_j = vmd[b * NQ + j_p];
        const bool em = (id_i >= 0) && (id_j >= 0) &&
                        ((id_i != id_j) || (!vm_i) || (!vm_j));
        float* oe1 = out_edge + (((size_t)(b * NQ) + i_p) * NQ + j_p) * 5;
        float* oe2 = out_edge + (((size_t)(b * NQ) + j_p) * NQ + i_p) * 5;
        #pragma unroll
        for (int q = 0; q < 5; ++q) {
            float vq = b_eo2[q] + oBuf[0][p][q] + oBuf[1][p][q]
                                + oBuf[2][p][q] + oBuf[3][p][q];
            vq = em ? vq : 0.0f;
            oe1[q] = vq;
            oe2[q] = vq;
        }
    }
}

extern "C" void kernel_launch(void* const* d_in, const int* in_sizes, int n_in,
                              void* d_out, int out_size, void* d_ws, size_t ws_size,
                              hipStream_t stream) {
    const float* node     = (const float*)d_in[0];
    const float* edge     = (const float*)d_in[1];
    const int*   block_id = (const int*)d_in[2];
    const void*  vm_raw   = d_in[3];
    const float* W_nt  = (const float*)d_in[4];
    const float* b_nt  = (const float*)d_in[5];
    const float* W_n1  = (const float*)d_in[6];
    const float* b_n1  = (const float*)d_in[7];
    const float* W_e1  = (const float*)d_in[8];
    const float* b_e1  = (const float*)d_in[9];
    const float* W_f1  = (const float*)d_in[10];
    const float* b_f1  = (const float*)d_in[11];
    const float* W_f2  = (const float*)d_in[12];
    const float* b_f2  = (const float*)d_in[13];
    const float* W_no1 = (const float*)d_in[14];
    const float* b_no1 = (const float*)d_in[15];
    const float* g_no  = (const float*)d_in[16];
    const float* be_no = (const float*)d_in[17];
    const float* W_no2 = (const float*)d_in[18];
    const float* b_no2 = (const float*)d_in[19];
    const float* W_eo1 = (const float*)d_in[20];
    const float* b_eo1 = (const float*)d_in[21];
    const float* g_eo  = (const float*)d_in[22];
    const float* be_eo = (const float*)d_in[23];
    const float* W_eo2 = (const float*)d_in[24];
    const float* b_eo2 = (const float*)d_in[25];

    char* ws = (char*)d_ws;
    int*   vmd  = (int*)ws;                         // 8 KB
    float* n_ws = (float*)(ws + 8192);              // 1 MB
    float* q1_ws = (float*)(ws + 8192 + (1 << 20)); // 512 KB
    float* q2_ws = (float*)(ws + 8192 + (1 << 20) + (512 << 10));
    float* out_node = (float*)d_out;
    float* out_edge = out_node + 4 * 512 * 10;

    decode_mask_kernel<<<1, 256, 0, stream>>>((const unsigned char*)vm_raw, vmd, 4 * 512);
    node_kernel<<<4 * 512, 128, 0, stream>>>(
        node, edge, block_id, vmd,
        W_nt, b_nt, W_n1, b_n1, W_f1, b_f1, W_no1, b_no1, g_no, be_no, W_no2, b_no2,
        n_ws, q1_ws, q2_ws, out_node);
    edge_kernel<<<8192 + 16, 256, 0, stream>>>(
        edge, block_id, vmd, n_ws, q1_ws, q2_ws,
        W_e1, b_e1, W_f2, b_f2,
        W_eo1, b_eo1, g_eo, be_eo, W_eo2, b_eo2, out_edge);
}